// Round 8
// baseline (1823.109 us; speedup 1.0000x reference)
//
#include <hip/hip_runtime.h>

#define DT_C 0.1f
#define LOG2E 1.4426950408889634f

typedef _Float16 h2 __attribute__((ext_vector_type(2)));

__device__ __forceinline__ float sigx(float z) {
    return __builtin_amdgcn_rcpf(1.0f + __builtin_amdgcn_exp2f(-LOG2E * z));
}
__device__ __forceinline__ float tanhx(float z) {
    return fmaf(2.0f, __builtin_amdgcn_rcpf(1.0f + __builtin_amdgcn_exp2f(-2.0f * LOG2E * z)), -1.0f);
}

// DPP ctrl must be a compile-time constant -> template parameter (R7 lesson).
template <int CTRL>
__device__ __forceinline__ float dpp_add(float v) {
    return v + __int_as_float(__builtin_amdgcn_update_dpp(0, __float_as_int(v), CTRL, 0xF, 0xF, true));
}
// 16-lane rotate-reduce on the VALU: row_ror:8 (0x128), row_ror:4 (0x124),
// quad xor2 (0x4E), quad xor1 (0xB1). All lanes end with the group-of-16 sum.
__device__ __forceinline__ float red16(float v) {
    v = dpp_add<0x128>(v);
    v = dpp_add<0x124>(v);
    v = dpp_add<0x4E>(v);
    v = dpp_add<0xB1>(v);
    return v;
}
// quad_perm [1,0,3,2]: partner swap q0<->q1, q2<->q3.
__device__ __forceinline__ float dppswap1(float v) {
    return __int_as_float(__builtin_amdgcn_update_dpp(0, __float_as_int(v), 0xB1, 0xF, 0xF, true));
}
// quad_perm [2,3,0,1]: q0<->q2, q1<->q3.
__device__ __forceinline__ float dppswap2(float v) {
    return __int_as_float(__builtin_amdgcn_update_dpp(0, __float_as_int(v), 0x4E, 0xF, 0xF, true));
}

__device__ __forceinline__ unsigned pk16(float lo, float hi) {
    return __builtin_bit_cast(unsigned, __builtin_amdgcn_cvt_pkrtz(lo, hi));
}

// B=256, S=2048, I=1, H=128, O=1.
// Grid: 256 blocks (1 row/CU). Block: 1024 threads (16 waves, 4/SIMD for
// latency hiding across the 2 per-step barriers). t = jg*16 + ks.
// Thread (jg,ks): output rows j0=jg, j1=jg+64; k-slice {4ks+i, 4ks+64+i}.
// h/hatt live in LDS as packed half2 {v[k], v[k+64]} -> whole slice is ONE
// ds_read_b128/phase. Matvecs via v_dot2_f32_f16 (full-rate, 2 MAC/lane/cyc —
// R6 lesson: v_pk_fma_f32 is HALF-rate on CDNA4, fp32 packing bought nothing).
// State (h, acc, ew, ic) and nonlinearities stay fp32; only matvec operands
// are f16. Lane-role nonlins (R6): q=ks&3 -> one nonlin computes 4 values.
__global__ __attribute__((amdgpu_waves_per_eu(4, 4))) __launch_bounds__(1024)
void clnm_kernel(const float* __restrict__ x,      // [256,2048]
                 const float* __restrict__ W_in,   // [128,1]
                 const float* __restrict__ b_in,   // [128]
                 const float* __restrict__ W_rec,  // [128,128]
                 const float* __restrict__ b_rec,  // [128]
                 const float* __restrict__ tau,    // [128]
                 const float* __restrict__ W_att,  // [128,128]
                 const float* __restrict__ b_att,  // [128]
                 const float* __restrict__ W_ev,   // [1,2]
                 const float* __restrict__ b_ev,   // [1]
                 const float* __restrict__ W_acc,  // [128,128]
                 const float* __restrict__ b_acc,  // [128]
                 const float* __restrict__ W_out,  // [1,128]
                 const float* __restrict__ b_out,  // [1]
                 float* __restrict__ out,          // [256]
                 float* __restrict__ out_ew)       // [256,2048]
{
    const int t  = threadIdx.x;
    const int jg = t >> 4;        // 0..63
    const int ks = t & 15;        // 0..15
    const int j0 = jg;
    const int j1 = jg + 64;
    const int r  = blockIdx.x;

    __shared__ __align__(16) float    x_stage[2048];
    __shared__ __align__(16) float4   xe_lds[2048];  // {x_{s+1}, DT(1+ew), 0.1ew, ew}
    __shared__ __align__(16) unsigned h16[64];       // packed {h[m], h[m+64]}
    __shared__ __align__(16) unsigned ha16[64];      // packed hatt
    __shared__ float red_s[16];

    const float wev0 = W_ev[0], wev1 = W_ev[1], bev = b_ev[0], bout = b_out[0];

    ((float2*)x_stage)[t] = ((const float2*)(x + (size_t)r * 2048))[t];
    if (t < 64) h16[t] = 0u;
    __syncthreads();

    // Per-step scalars, 2 steps/thread; out_ew coalesced float2.
    {
        const int s0 = t * 2;
        const float x0 = x_stage[s0], x1 = x_stage[s0 + 1];
        const float xm1 = (t == 0) ? 0.0f : x_stage[s0 - 1];
        const float x2  = (s0 + 2 < 2048) ? x_stage[s0 + 2] : 0.0f;
        const float e0 = (s0 == 0) ? 0.0f : sigx(fmaf(wev0, x0, fmaf(wev1, xm1, bev)));
        const float e1 = sigx(fmaf(wev0, x1, fmaf(wev1, x0, bev)));
        xe_lds[s0 + 0] = make_float4(x1, DT_C * (1.0f + e0), 0.1f * e0, e0);
        xe_lds[s0 + 1] = make_float4(x2, DT_C * (1.0f + e1), 0.1f * e1, e1);
        ((float2*)(out_ew + (size_t)r * 2048))[t] = make_float2(e0, e1);
    }

    // Weights as half2 pairs {W[g][4ks+i], W[g][4ks+64+i]} matching LDS packing.
    h2 wA[2][4], wR[2][4], wC[2][4];
#pragma unroll
    for (int g = 0; g < 2; ++g) {
        const int base = (g ? j1 : j0) * 128 + 4 * ks;
#pragma unroll
        for (int i = 0; i < 4; ++i) {
            wA[g][i] = h2{(_Float16)W_att[base + i], (_Float16)W_att[base + 64 + i]};
            wR[g][i] = h2{(_Float16)W_rec[base + i], (_Float16)W_rec[base + 64 + i]};
            wC[g][i] = h2{(_Float16)W_acc[base + i], (_Float16)W_acc[base + 64 + i]};
        }
    }

    // Lane roles (q = ks&3): q0 rec/att row j0, q1 rec/att row j1,
    // q2 ic/acc row j0, q3 ic/acc row j1.
    const bool odd = (ks & 1) != 0;
    const bool low = (ks & 2) == 0;
    const float bRsel  = odd ? b_rec[j1] : b_rec[j0];
    const float winsel = odd ? W_in[j1]  : W_in[j0];
    const float binsel = odd ? b_in[j1]  : b_in[j0];
    const float bFsel  = low ? (odd ? b_att[j1] : b_att[j0])
                             : (odd ? b_acc[j1] : b_acc[j0]);
    const float preF   = low ? -LOG2E : -2.0f * LOG2E;   // sigmoid vs tanh
    const float postm  = low ? 1.0f : 2.0f;
    const float posta  = low ? 0.0f : -1.0f;
    const float tisel  = 1.0f / fminf(fmaxf(odd ? tau[j1] : tau[j0], 0.1f), 10.0f);
    const float wosel  = odd ? W_out[j1] : W_out[j0];

    __syncthreads();   // h16 zeros + xe_lds visible

    float hjs = 0.0f, acs = 0.0f;
    // att(h_0=0) on q0/q1 lanes: nonlin of bias alone.
    float attv = fmaf(postm, __builtin_amdgcn_rcpf(1.0f + __builtin_amdgcn_exp2f(preF * bFsel)), posta);
    // ic for step 0 (q0/q1 lanes compute their own row's ic).
    float iccur = tanhx(fmaf(x_stage[0], winsel, binsel));

    const uint4* h4p  = (const uint4*)h16;
    const uint4* ha4p = (const uint4*)ha16;

    for (int s = 0; s < 2048; ++s) {
        // hatt packed write: q0 lane owns {hatt[j0], hatt[j1]} via partner swap.
        {
            const float hav  = hjs * attv;        // valid q0/q1
            const float havo = dppswap1(hav);
            if (ks == 0) ha16[jg] = pk16(hav, havo);
        }
        __syncthreads();   // A: hatt(h_s) visible

        const uint4 au = ha4p[ks];
        const float4 xe = xe_lds[s];   // {x_{s+1}, kk, ewp, ew}
        const h2 a0 = __builtin_bit_cast(h2, au.x), a1 = __builtin_bit_cast(h2, au.y);
        const h2 a2 = __builtin_bit_cast(h2, au.z), a3 = __builtin_bit_cast(h2, au.w);

        // ---- REC matvec: 8 dot2 (2 rows x 2 chains) ----
        float rA0 = __builtin_amdgcn_fdot2(wR[0][0], a0, __builtin_amdgcn_fdot2(wR[0][2], a2, 0.0f, false), false);
        float rB0 = __builtin_amdgcn_fdot2(wR[0][1], a1, __builtin_amdgcn_fdot2(wR[0][3], a3, 0.0f, false), false);
        float rA1 = __builtin_amdgcn_fdot2(wR[1][0], a0, __builtin_amdgcn_fdot2(wR[1][2], a2, 0.0f, false), false);
        float rB1 = __builtin_amdgcn_fdot2(wR[1][1], a1, __builtin_amdgcn_fdot2(wR[1][3], a3, 0.0f, false), false);
        const float rsum0 = red16(rA0 + rB0);
        const float rsum1 = red16(rA1 + rB1);

        // ONE tanh: q0/q1 -> rec(j0/j1); q2/q3 -> ic_{s+1}(j0/j1).
        const float zsel = low ? ((odd ? rsum1 : rsum0) + bRsel)
                               : fmaf(xe.x, winsel, binsel);
        const float tres = tanhx(zsel);
        const float icn  = dppswap2(tres);

        // h update (valid q0/q1): h += kk*ti * ((ic+rec) - h)
        hjs = fmaf(xe.y * tisel, (iccur + tres) - hjs, hjs);
        iccur = icn;
        {
            const float ho = dppswap1(hjs);
            if (ks == 0) h16[jg] = pk16(hjs, ho);
        }
        __syncthreads();   // B: h_{s+1} visible

        const uint4 hu = h4p[ks];
        const h2 h0 = __builtin_bit_cast(h2, hu.x), h1 = __builtin_bit_cast(h2, hu.y);
        const h2 hh2 = __builtin_bit_cast(h2, hu.z), h3 = __builtin_bit_cast(h2, hu.w);

        // ---- FUSED ATT+ACC matvec on h_{s+1}: 16 dot2, 8 chains ----
        float aA0 = __builtin_amdgcn_fdot2(wA[0][0], h0, __builtin_amdgcn_fdot2(wA[0][2], hh2, 0.0f, false), false);
        float aB0 = __builtin_amdgcn_fdot2(wA[0][1], h1, __builtin_amdgcn_fdot2(wA[0][3], h3, 0.0f, false), false);
        float aA1 = __builtin_amdgcn_fdot2(wA[1][0], h0, __builtin_amdgcn_fdot2(wA[1][2], hh2, 0.0f, false), false);
        float aB1 = __builtin_amdgcn_fdot2(wA[1][1], h1, __builtin_amdgcn_fdot2(wA[1][3], h3, 0.0f, false), false);
        float cA0 = __builtin_amdgcn_fdot2(wC[0][0], h0, __builtin_amdgcn_fdot2(wC[0][2], hh2, 0.0f, false), false);
        float cB0 = __builtin_amdgcn_fdot2(wC[0][1], h1, __builtin_amdgcn_fdot2(wC[0][3], h3, 0.0f, false), false);
        float cA1 = __builtin_amdgcn_fdot2(wC[1][0], h0, __builtin_amdgcn_fdot2(wC[1][2], hh2, 0.0f, false), false);
        float cB1 = __builtin_amdgcn_fdot2(wC[1][1], h1, __builtin_amdgcn_fdot2(wC[1][3], h3, 0.0f, false), false);
        const float asum0 = red16(aA0 + aB0);
        const float asum1 = red16(aA1 + aB1);
        const float csum0 = red16(cA0 + cB0);
        const float csum1 = red16(cA1 + cB1);

        // ONE nonlin: q0/q1 -> att sigmoid, q2/q3 -> acc tanh.
        const float zf = (low ? (odd ? asum1 : asum0) : (odd ? csum1 : csum0)) + bFsel;
        const float fres = fmaf(postm,
            __builtin_amdgcn_rcpf(1.0f + __builtin_amdgcn_exp2f(preF * zf)), posta);

        attv = fres;                           // valid q0/q1
        acs  = fmaf(xe.z, fres, 0.9f * acs);   // valid q2/q3
    }

    // ---- Output: out[r] = sum_j (h_f + acc_f)[j] * W_out[j] + b_out ----
    float val = (ks < 4) ? (low ? hjs : acs) * wosel : 0.0f;
#pragma unroll
    for (int m = 1; m < 64; m <<= 1) val += __shfl_xor(val, m);
    const int wave = t >> 6, lane = t & 63;
    if (lane == 0) red_s[wave] = val;
    __syncthreads();
    if (t == 0) {
        float o = bout;
#pragma unroll
        for (int w = 0; w < 16; ++w) o += red_s[w];
        out[r] = o;
    }
}

extern "C" void kernel_launch(void* const* d_in, const int* in_sizes, int n_in,
                              void* d_out, int out_size, void* d_ws, size_t ws_size,
                              hipStream_t stream) {
    const float* x     = (const float*)d_in[0];
    const float* W_in  = (const float*)d_in[1];
    const float* b_in  = (const float*)d_in[2];
    const float* W_rec = (const float*)d_in[3];
    const float* b_rec = (const float*)d_in[4];
    const float* tau   = (const float*)d_in[5];
    const float* W_att = (const float*)d_in[6];
    const float* b_att = (const float*)d_in[7];
    const float* W_ev  = (const float*)d_in[8];
    const float* b_ev  = (const float*)d_in[9];
    const float* W_acc = (const float*)d_in[10];
    const float* b_acc = (const float*)d_in[11];
    const float* W_out = (const float*)d_in[12];
    const float* b_out = (const float*)d_in[13];

    float* out    = (float*)d_out;        // [256,1]
    float* out_ew = out + 256;            // [256,2048]

    clnm_kernel<<<256, 1024, 0, stream>>>(x, W_in, b_in, W_rec, b_rec, tau,
                                          W_att, b_att, W_ev, b_ev,
                                          W_acc, b_acc, W_out, b_out,
                                          out, out_ew);
}

// Round 9
// 1314.373 us; speedup vs baseline: 1.3871x; 1.3871x over previous
//
#include <hip/hip_runtime.h>

#define DT_C 0.1f
#define LOG2E 1.4426950408889634f

typedef _Float16 h2 __attribute__((ext_vector_type(2)));

__device__ __forceinline__ float sigx(float z) {
    return __builtin_amdgcn_rcpf(1.0f + __builtin_amdgcn_exp2f(-LOG2E * z));
}
__device__ __forceinline__ float tanhx(float z) {
    return fmaf(2.0f, __builtin_amdgcn_rcpf(1.0f + __builtin_amdgcn_exp2f(-2.0f * LOG2E * z)), -1.0f);
}

// DPP ctrl must be an ICE -> template param (R7 lesson).
template <int CTRL>
__device__ __forceinline__ float dpp_add(float v) {
    return v + __int_as_float(__builtin_amdgcn_update_dpp(0, __float_as_int(v), CTRL, 0xF, 0xF, true));
}
// 8-lane butterfly sum (aligned groups of 8): xor1 (quad 0xB1), xor2 (quad
// 0x4E), xor7 (row_half_mirror 0x141). HW-verified R2-R6.
__device__ __forceinline__ float red8(float v) {
    v = dpp_add<0xB1>(v);
    v = dpp_add<0x4E>(v);
    v = dpp_add<0x141>(v);
    return v;
}
// quad_perm [1,0,3,2]: partner swap q0<->q1, q2<->q3.
__device__ __forceinline__ float dppswap1(float v) {
    return __int_as_float(__builtin_amdgcn_update_dpp(0, __float_as_int(v), 0xB1, 0xF, 0xF, true));
}
// quad_perm [2,3,0,1]: q0<->q2, q1<->q3.
__device__ __forceinline__ float dppswap2(float v) {
    return __int_as_float(__builtin_amdgcn_update_dpp(0, __float_as_int(v), 0x4E, 0xF, 0xF, true));
}

__device__ __forceinline__ unsigned pk16(float lo, float hi) {
    return __builtin_bit_cast(unsigned, __builtin_amdgcn_cvt_pkrtz(lo, hi));
}
__device__ __forceinline__ float fdot2(h2 a, h2 b, float c) {
    return __builtin_amdgcn_fdot2(a, b, c, false);
}

// B=256, S=2048, I=1, H=128, O=1.
// Grid: 256 blocks (1 row/CU). Block: 512 threads = 2 waves/SIMD (R8 lesson:
// 1024 threads doubled per-thread FIXED overhead per SIMD — reductions/nonlins
// /role logic scale with thread count, only matvec work divides).
// t = jg*8+ks. Thread (jg,ks): rows j0=jg, j1=jg+64; k-pairs {k, k+64} for
// k in [8ks, 8ks+8) — h/hatt packed in LDS as half2 {v[k], v[k+64]} so a
// slice is 2x ds_read_b128 (2-way bank alias = free, m136).
// Matvecs: v_dot2_f32_f16 (f32 accumulate); state/nonlins stay fp32.
// Lane-role nonlins (R6): q=ks&3 -> one nonlin sequence covers 4 values.
__global__ __attribute__((amdgpu_waves_per_eu(2, 2))) __launch_bounds__(512)
void clnm_kernel(const float* __restrict__ x,      // [256,2048]
                 const float* __restrict__ W_in,   // [128,1]
                 const float* __restrict__ b_in,   // [128]
                 const float* __restrict__ W_rec,  // [128,128]
                 const float* __restrict__ b_rec,  // [128]
                 const float* __restrict__ tau,    // [128]
                 const float* __restrict__ W_att,  // [128,128]
                 const float* __restrict__ b_att,  // [128]
                 const float* __restrict__ W_ev,   // [1,2]
                 const float* __restrict__ b_ev,   // [1]
                 const float* __restrict__ W_acc,  // [128,128]
                 const float* __restrict__ b_acc,  // [128]
                 const float* __restrict__ W_out,  // [1,128]
                 const float* __restrict__ b_out,  // [1]
                 float* __restrict__ out,          // [256]
                 float* __restrict__ out_ew)       // [256,2048]
{
    const int t  = threadIdx.x;
    const int jg = t >> 3;        // 0..63
    const int ks = t & 7;         // 0..7
    const int j0 = jg;
    const int j1 = jg + 64;
    const int r  = blockIdx.x;

    __shared__ __align__(16) float    x_stage[2048];
    __shared__ __align__(16) float4   xe_lds[2048];  // {x_{s+1}, DT(1+ew), 0.1ew, ew}
    __shared__ __align__(16) unsigned h16[64];       // packed {h[k], h[k+64]}
    __shared__ __align__(16) unsigned ha16[64];      // packed hatt
    __shared__ float red_s[8];

    const float wev0 = W_ev[0], wev1 = W_ev[1], bev = b_ev[0], bout = b_out[0];

    ((float4*)x_stage)[t] = ((const float4*)(x + (size_t)r * 2048))[t];
    if (t < 64) h16[t] = 0u;
    __syncthreads();

    // Per-step scalars, 4 steps/thread; out_ew coalesced float4 (exact fp32).
    {
        const int s0 = t * 4;
        const float x0 = x_stage[s0], x1 = x_stage[s0 + 1];
        const float x2 = x_stage[s0 + 2], x3 = x_stage[s0 + 3];
        const float xm1 = (t == 0) ? 0.0f : x_stage[s0 - 1];
        const float x4  = (s0 + 4 < 2048) ? x_stage[s0 + 4] : 0.0f;
        const float e0 = (s0 == 0) ? 0.0f : sigx(fmaf(wev0, x0, fmaf(wev1, xm1, bev)));
        const float e1 = sigx(fmaf(wev0, x1, fmaf(wev1, x0, bev)));
        const float e2 = sigx(fmaf(wev0, x2, fmaf(wev1, x1, bev)));
        const float e3 = sigx(fmaf(wev0, x3, fmaf(wev1, x2, bev)));
        xe_lds[s0 + 0] = make_float4(x1, DT_C * (1.0f + e0), 0.1f * e0, e0);
        xe_lds[s0 + 1] = make_float4(x2, DT_C * (1.0f + e1), 0.1f * e1, e1);
        xe_lds[s0 + 2] = make_float4(x3, DT_C * (1.0f + e2), 0.1f * e2, e2);
        xe_lds[s0 + 3] = make_float4(x4, DT_C * (1.0f + e3), 0.1f * e3, e3);
        ((float4*)(out_ew + (size_t)r * 2048))[t] = make_float4(e0, e1, e2, e3);
    }

    // Weights as half2 pairs {W[row][8ks+i], W[row][8ks+64+i]}, i<8. 48 VGPRs.
    h2 wA[2][8], wR[2][8], wC[2][8];
#pragma unroll
    for (int g = 0; g < 2; ++g) {
        const int base = (g ? j1 : j0) * 128 + 8 * ks;
#pragma unroll
        for (int i = 0; i < 8; ++i) {
            wA[g][i] = h2{(_Float16)W_att[base + i], (_Float16)W_att[base + 64 + i]};
            wR[g][i] = h2{(_Float16)W_rec[base + i], (_Float16)W_rec[base + 64 + i]};
            wC[g][i] = h2{(_Float16)W_acc[base + i], (_Float16)W_acc[base + 64 + i]};
        }
    }

    // Lane roles (q = ks&3): q0 rec/att row j0, q1 rec/att row j1,
    // q2 ic/acc row j0, q3 ic/acc row j1. (Duplicated at ks>=4; writers ks==0.)
    const bool odd = (ks & 1) != 0;
    const bool low = (ks & 2) == 0;
    const float bRsel  = odd ? b_rec[j1] : b_rec[j0];
    const float winsel = odd ? W_in[j1]  : W_in[j0];
    const float binsel = odd ? b_in[j1]  : b_in[j0];
    const float bFsel  = low ? (odd ? b_att[j1] : b_att[j0])
                             : (odd ? b_acc[j1] : b_acc[j0]);
    const float preF   = low ? -LOG2E : -2.0f * LOG2E;   // sigmoid vs tanh
    const float postm  = low ? 1.0f : 2.0f;
    const float posta  = low ? 0.0f : -1.0f;
    const float tisel  = 1.0f / fminf(fmaxf(odd ? tau[j1] : tau[j0], 0.1f), 10.0f);
    const float wosel  = odd ? W_out[j1] : W_out[j0];

    __syncthreads();   // h16 zeros + xe_lds visible

    float hjs = 0.0f, acs = 0.0f;
    float attv = fmaf(postm, __builtin_amdgcn_rcpf(1.0f + __builtin_amdgcn_exp2f(preF * bFsel)), posta);
    float iccur = tanhx(fmaf(x_stage[0], winsel, binsel));

    const uint4* h4p  = (const uint4*)h16;    // index 2ks, 2ks+1
    const uint4* ha4p = (const uint4*)ha16;

    for (int s = 0; s < 2048; ++s) {
        // Publish hatt (packed): ks==0 packs own (row j0) + partner's (row j1).
        {
            const float hav  = hjs * attv;        // valid on q0/q1 lanes
            const float havo = dppswap1(hav);
            if (ks == 0) ha16[jg] = pk16(hav, havo);
        }
        __syncthreads();   // A: hatt(h_s) visible

        const uint4 au0 = ha4p[2 * ks], au1 = ha4p[2 * ks + 1];
        const float4 xe = xe_lds[s];   // {x_{s+1}, kk, ewp, ew}
        const h2 a0 = __builtin_bit_cast(h2, au0.x), a1 = __builtin_bit_cast(h2, au0.y);
        const h2 a2 = __builtin_bit_cast(h2, au0.z), a3 = __builtin_bit_cast(h2, au0.w);
        const h2 a4 = __builtin_bit_cast(h2, au1.x), a5 = __builtin_bit_cast(h2, au1.y);
        const h2 a6 = __builtin_bit_cast(h2, au1.z), a7 = __builtin_bit_cast(h2, au1.w);

        // ---- REC matvec: 16 dot2, 4 chains of depth 4 ----
        float r0a = fdot2(wR[0][6], a6, fdot2(wR[0][4], a4, fdot2(wR[0][2], a2, fdot2(wR[0][0], a0, 0.0f))));
        float r0b = fdot2(wR[0][7], a7, fdot2(wR[0][5], a5, fdot2(wR[0][3], a3, fdot2(wR[0][1], a1, 0.0f))));
        float r1a = fdot2(wR[1][6], a6, fdot2(wR[1][4], a4, fdot2(wR[1][2], a2, fdot2(wR[1][0], a0, 0.0f))));
        float r1b = fdot2(wR[1][7], a7, fdot2(wR[1][5], a5, fdot2(wR[1][3], a3, fdot2(wR[1][1], a1, 0.0f))));
        const float rsum0 = red8(r0a + r0b);
        const float rsum1 = red8(r1a + r1b);

        // ONE tanh: q0/q1 -> rec(j0/j1); q2/q3 -> ic_{s+1}(j0/j1).
        const float zsel = low ? ((odd ? rsum1 : rsum0) + bRsel)
                               : fmaf(xe.x, winsel, binsel);
        const float tres = tanhx(zsel);
        const float icn  = dppswap2(tres);

        // h update (valid on q0/q1 lanes): h += kk*ti * ((ic+rec) - h)
        hjs = fmaf(xe.y * tisel, (iccur + tres) - hjs, hjs);
        iccur = icn;
        {
            const float ho = dppswap1(hjs);
            if (ks == 0) h16[jg] = pk16(hjs, ho);
        }
        __syncthreads();   // B: h_{s+1} visible

        const uint4 hu0 = h4p[2 * ks], hu1 = h4p[2 * ks + 1];
        const h2 g0 = __builtin_bit_cast(h2, hu0.x), g1 = __builtin_bit_cast(h2, hu0.y);
        const h2 g2 = __builtin_bit_cast(h2, hu0.z), g3 = __builtin_bit_cast(h2, hu0.w);
        const h2 g4 = __builtin_bit_cast(h2, hu1.x), g5 = __builtin_bit_cast(h2, hu1.y);
        const h2 g6 = __builtin_bit_cast(h2, hu1.z), g7 = __builtin_bit_cast(h2, hu1.w);

        // ---- FUSED ATT+ACC matvec on h_{s+1}: 32 dot2, 8 chains ----
        float aa0 = fdot2(wA[0][6], g6, fdot2(wA[0][4], g4, fdot2(wA[0][2], g2, fdot2(wA[0][0], g0, 0.0f))));
        float ab0 = fdot2(wA[0][7], g7, fdot2(wA[0][5], g5, fdot2(wA[0][3], g3, fdot2(wA[0][1], g1, 0.0f))));
        float aa1 = fdot2(wA[1][6], g6, fdot2(wA[1][4], g4, fdot2(wA[1][2], g2, fdot2(wA[1][0], g0, 0.0f))));
        float ab1 = fdot2(wA[1][7], g7, fdot2(wA[1][5], g5, fdot2(wA[1][3], g3, fdot2(wA[1][1], g1, 0.0f))));
        float ca0 = fdot2(wC[0][6], g6, fdot2(wC[0][4], g4, fdot2(wC[0][2], g2, fdot2(wC[0][0], g0, 0.0f))));
        float cb0 = fdot2(wC[0][7], g7, fdot2(wC[0][5], g5, fdot2(wC[0][3], g3, fdot2(wC[0][1], g1, 0.0f))));
        float ca1 = fdot2(wC[1][6], g6, fdot2(wC[1][4], g4, fdot2(wC[1][2], g2, fdot2(wC[1][0], g0, 0.0f))));
        float cb1 = fdot2(wC[1][7], g7, fdot2(wC[1][5], g5, fdot2(wC[1][3], g3, fdot2(wC[1][1], g1, 0.0f))));
        const float asum0 = red8(aa0 + ab0);
        const float asum1 = red8(aa1 + ab1);
        const float csum0 = red8(ca0 + cb0);
        const float csum1 = red8(ca1 + cb1);

        // ONE nonlin: q0/q1 -> att sigmoid, q2/q3 -> acc tanh.
        const float zf = (low ? (odd ? asum1 : asum0) : (odd ? csum1 : csum0)) + bFsel;
        const float fres = fmaf(postm,
            __builtin_amdgcn_rcpf(1.0f + __builtin_amdgcn_exp2f(preF * zf)), posta);

        attv = fres;                           // valid q0/q1
        acs  = fmaf(xe.z, fres, 0.9f * acs);   // valid q2/q3
    }

    // ---- Output: out[r] = sum_j (h_f + acc_f)[j] * W_out[j] + b_out ----
    float val = (ks < 4) ? (low ? hjs : acs) * wosel : 0.0f;
#pragma unroll
    for (int m = 1; m < 64; m <<= 1) val += __shfl_xor(val, m);
    const int wave = t >> 6, lane = t & 63;
    if (lane == 0) red_s[wave] = val;
    __syncthreads();
    if (t == 0) {
        float o = bout;
#pragma unroll
        for (int w = 0; w < 8; ++w) o += red_s[w];
        out[r] = o;
    }
}

extern "C" void kernel_launch(void* const* d_in, const int* in_sizes, int n_in,
                              void* d_out, int out_size, void* d_ws, size_t ws_size,
                              hipStream_t stream) {
    const float* x     = (const float*)d_in[0];
    const float* W_in  = (const float*)d_in[1];
    const float* b_in  = (const float*)d_in[2];
    const float* W_rec = (const float*)d_in[3];
    const float* b_rec = (const float*)d_in[4];
    const float* tau   = (const float*)d_in[5];
    const float* W_att = (const float*)d_in[6];
    const float* b_att = (const float*)d_in[7];
    const float* W_ev  = (const float*)d_in[8];
    const float* b_ev  = (const float*)d_in[9];
    const float* W_acc = (const float*)d_in[10];
    const float* b_acc = (const float*)d_in[11];
    const float* W_out = (const float*)d_in[12];
    const float* b_out = (const float*)d_in[13];

    float* out    = (float*)d_out;        // [256,1]
    float* out_ew = out + 256;            // [256,2048]

    clnm_kernel<<<256, 512, 0, stream>>>(x, W_in, b_in, W_rec, b_rec, tau,
                                         W_att, b_att, W_ev, b_ev,
                                         W_acc, b_acc, W_out, b_out,
                                         out, out_ew);
}

// Round 10
// 1233.231 us; speedup vs baseline: 1.4783x; 1.0658x over previous
//
#include <hip/hip_runtime.h>

#define DT_C 0.1f
#define LOG2E 1.4426950408889634f

typedef _Float16 h2 __attribute__((ext_vector_type(2)));

__device__ __forceinline__ float sigx(float z) {
    return __builtin_amdgcn_rcpf(1.0f + __builtin_amdgcn_exp2f(-LOG2E * z));
}
__device__ __forceinline__ float tanhx(float z) {
    return fmaf(2.0f, __builtin_amdgcn_rcpf(1.0f + __builtin_amdgcn_exp2f(-2.0f * LOG2E * z)), -1.0f);
}

template <int CTRL>
__device__ __forceinline__ float dpp_add(float v) {
    return v + __int_as_float(__builtin_amdgcn_update_dpp(0, __float_as_int(v), CTRL, 0xF, 0xF, true));
}
// 4-lane butterfly sum (aligned quads): xor1 (0xB1) + xor2 (0x4E).
__device__ __forceinline__ float red4(float v) {
    v = dpp_add<0xB1>(v);
    v = dpp_add<0x4E>(v);
    return v;
}
// quad_perm [1,0,3,2]: partner swap q0<->q1, q2<->q3.
__device__ __forceinline__ float dppswap1(float v) {
    return __int_as_float(__builtin_amdgcn_update_dpp(0, __float_as_int(v), 0xB1, 0xF, 0xF, true));
}
// quad_perm [2,3,0,1]: q0<->q2, q1<->q3.
__device__ __forceinline__ float dppswap2(float v) {
    return __int_as_float(__builtin_amdgcn_update_dpp(0, __float_as_int(v), 0x4E, 0xF, 0xF, true));
}

__device__ __forceinline__ unsigned pk16(float lo, float hi) {
    return __builtin_bit_cast(unsigned, __builtin_amdgcn_cvt_pkrtz(lo, hi));
}
__device__ __forceinline__ float fdot2(h2 a, h2 b, float c) {
    return __builtin_amdgcn_fdot2(a, b, c, false);
}

// B=256, S=2048, I=1, H=128, O=1.
// Grid: 256 blocks (1 row/CU). Block: 256 threads = 4 waves = 1 wave/SIMD.
// R10 (inverse of R8's lesson): total issue/CU = per-thread fixed overhead x
// thread count. At 512 thr, 8 ks-lanes duplicated 4 roles and red8 cost 3 DPP;
// at 256 thr the 4 lanes/group ARE the 4 roles (zero dup), red4 = 2 DPP, and
// every fixed cost (nonlins, LDS reads, xe, loop) is paid by half the waves.
// Matvec total is unchanged (wider slices: 32 k/thread).
// t = jg*4+ks. Thread (jg,ks): rows j0=jg, j1=jg+64; packed k-pairs
// m in [16ks,16ks+16) where h16[m]={h[m],h[m+64]} (4x ds_read_b128, 2-way
// bank alias = free). Matvecs: v_dot2_f32_f16, f32 state/nonlins.
__global__ __attribute__((amdgpu_waves_per_eu(1, 1))) __launch_bounds__(256)
void clnm_kernel(const float* __restrict__ x,      // [256,2048]
                 const float* __restrict__ W_in,   // [128,1]
                 const float* __restrict__ b_in,   // [128]
                 const float* __restrict__ W_rec,  // [128,128]
                 const float* __restrict__ b_rec,  // [128]
                 const float* __restrict__ tau,    // [128]
                 const float* __restrict__ W_att,  // [128,128]
                 const float* __restrict__ b_att,  // [128]
                 const float* __restrict__ W_ev,   // [1,2]
                 const float* __restrict__ b_ev,   // [1]
                 const float* __restrict__ W_acc,  // [128,128]
                 const float* __restrict__ b_acc,  // [128]
                 const float* __restrict__ W_out,  // [1,128]
                 const float* __restrict__ b_out,  // [1]
                 float* __restrict__ out,          // [256]
                 float* __restrict__ out_ew)       // [256,2048]
{
    const int t  = threadIdx.x;
    const int jg = t >> 2;        // 0..63
    const int ks = t & 3;         // 0..3 == role
    const int j0 = jg;
    const int j1 = jg + 64;
    const int r  = blockIdx.x;

    __shared__ __align__(16) float    x_stage[2048];
    __shared__ __align__(16) float4   xe_lds[2048];  // {x_{s+1}, DT(1+ew), 0.1ew, ew}
    __shared__ __align__(16) unsigned h16[64];       // packed {h[m], h[m+64]}
    __shared__ __align__(16) unsigned ha16[64];      // packed hatt
    __shared__ float red_s[4];

    const float wev0 = W_ev[0], wev1 = W_ev[1], bev = b_ev[0], bout = b_out[0];

    ((float4*)x_stage)[t]       = ((const float4*)(x + (size_t)r * 2048))[t];
    ((float4*)x_stage)[t + 256] = ((const float4*)(x + (size_t)r * 2048))[t + 256];
    if (t < 64) h16[t] = 0u;
    __syncthreads();

    // Per-step scalars, 8 steps/thread; out_ew coalesced float4 (exact fp32).
    {
        const int s0 = t * 8;
        float xv[9];
#pragma unroll
        for (int i = 0; i < 8; ++i) xv[i] = x_stage[s0 + i];
        xv[8] = (s0 + 8 < 2048) ? x_stage[s0 + 8] : 0.0f;
        const float xm1 = (t == 0) ? 0.0f : x_stage[s0 - 1];
        float e[8];
        e[0] = (s0 == 0) ? 0.0f : sigx(fmaf(wev0, xv[0], fmaf(wev1, xm1, bev)));
#pragma unroll
        for (int i = 1; i < 8; ++i)
            e[i] = sigx(fmaf(wev0, xv[i], fmaf(wev1, xv[i - 1], bev)));
#pragma unroll
        for (int i = 0; i < 8; ++i)
            xe_lds[s0 + i] = make_float4(xv[i + 1], DT_C * (1.0f + e[i]), 0.1f * e[i], e[i]);
        ((float4*)(out_ew + (size_t)r * 2048))[2 * t]     = make_float4(e[0], e[1], e[2], e[3]);
        ((float4*)(out_ew + (size_t)r * 2048))[2 * t + 1] = make_float4(e[4], e[5], e[6], e[7]);
    }

    // Weights as half2 pairs {W[row][m], W[row][m+64]}, m = 16ks+i, i<16.
    // 96 h2 = 96 VGPRs (1 wave/EU -> up to 512 budget).
    h2 wA[2][16], wR[2][16], wC[2][16];
#pragma unroll
    for (int g = 0; g < 2; ++g) {
        const int base = (g ? j1 : j0) * 128 + 16 * ks;
#pragma unroll
        for (int i = 0; i < 16; ++i) {
            wA[g][i] = h2{(_Float16)W_att[base + i], (_Float16)W_att[base + 64 + i]};
            wR[g][i] = h2{(_Float16)W_rec[base + i], (_Float16)W_rec[base + 64 + i]};
            wC[g][i] = h2{(_Float16)W_acc[base + i], (_Float16)W_acc[base + 64 + i]};
        }
    }

    // Lane roles (exact, ks==role): 0: rec/att j0, 1: rec/att j1,
    // 2: ic/acc j0, 3: ic/acc j1.
    const bool odd = (ks & 1) != 0;
    const bool low = (ks & 2) == 0;
    const float bRsel  = odd ? b_rec[j1] : b_rec[j0];
    const float winsel = odd ? W_in[j1]  : W_in[j0];
    const float binsel = odd ? b_in[j1]  : b_in[j0];
    const float bFsel  = low ? (odd ? b_att[j1] : b_att[j0])
                             : (odd ? b_acc[j1] : b_acc[j0]);
    const float preF   = low ? -LOG2E : -2.0f * LOG2E;   // sigmoid vs tanh
    const float postm  = low ? 1.0f : 2.0f;
    const float posta  = low ? 0.0f : -1.0f;
    const float tisel  = 1.0f / fminf(fmaxf(odd ? tau[j1] : tau[j0], 0.1f), 10.0f);
    const float wosel  = odd ? W_out[j1] : W_out[j0];

    __syncthreads();   // h16 zeros + xe_lds visible

    float hjs = 0.0f, acs = 0.0f;
    float attv = fmaf(postm, __builtin_amdgcn_rcpf(1.0f + __builtin_amdgcn_exp2f(preF * bFsel)), posta);
    float iccur = tanhx(fmaf(x_stage[0], winsel, binsel));

    const uint4* h4p  = (const uint4*)h16;    // thread reads [4ks .. 4ks+3]
    const uint4* ha4p = (const uint4*)ha16;

    for (int s = 0; s < 2048; ++s) {
        // Publish hatt (packed): ks==0 packs own (j0) + partner's (j1).
        {
            const float hav  = hjs * attv;        // valid on roles 0/1
            const float havo = dppswap1(hav);
            if (ks == 0) ha16[jg] = pk16(hav, havo);
        }
        __syncthreads();   // A: hatt(h_s) visible

        const uint4 au0 = ha4p[4 * ks + 0], au1 = ha4p[4 * ks + 1];
        const uint4 au2 = ha4p[4 * ks + 2], au3 = ha4p[4 * ks + 3];
        const float4 xe = xe_lds[s];   // {x_{s+1}, kk, ewp, ew}
        h2 a[16];
        a[0]  = __builtin_bit_cast(h2, au0.x); a[1]  = __builtin_bit_cast(h2, au0.y);
        a[2]  = __builtin_bit_cast(h2, au0.z); a[3]  = __builtin_bit_cast(h2, au0.w);
        a[4]  = __builtin_bit_cast(h2, au1.x); a[5]  = __builtin_bit_cast(h2, au1.y);
        a[6]  = __builtin_bit_cast(h2, au1.z); a[7]  = __builtin_bit_cast(h2, au1.w);
        a[8]  = __builtin_bit_cast(h2, au2.x); a[9]  = __builtin_bit_cast(h2, au2.y);
        a[10] = __builtin_bit_cast(h2, au2.z); a[11] = __builtin_bit_cast(h2, au2.w);
        a[12] = __builtin_bit_cast(h2, au3.x); a[13] = __builtin_bit_cast(h2, au3.y);
        a[14] = __builtin_bit_cast(h2, au3.z); a[15] = __builtin_bit_cast(h2, au3.w);

        // ---- REC matvec: 32 dot2, 4 chains of depth 8 ----
        float r0a = 0.0f, r0b = 0.0f, r1a = 0.0f, r1b = 0.0f;
#pragma unroll
        for (int i = 0; i < 8; ++i) {
            r0a = fdot2(wR[0][i],     a[i],     r0a);
            r0b = fdot2(wR[0][i + 8], a[i + 8], r0b);
            r1a = fdot2(wR[1][i],     a[i],     r1a);
            r1b = fdot2(wR[1][i + 8], a[i + 8], r1b);
        }
        const float rsum0 = red4(r0a + r0b);
        const float rsum1 = red4(r1a + r1b);

        // ONE tanh: roles 0/1 -> rec(j0/j1); roles 2/3 -> ic_{s+1}(j0/j1).
        const float zsel = low ? ((odd ? rsum1 : rsum0) + bRsel)
                               : fmaf(xe.x, winsel, binsel);
        const float tres = tanhx(zsel);
        const float icn  = dppswap2(tres);

        // h update (valid on roles 0/1): h += kk*ti * ((ic+rec) - h)
        hjs = fmaf(xe.y * tisel, (iccur + tres) - hjs, hjs);
        iccur = icn;
        {
            const float ho = dppswap1(hjs);
            if (ks == 0) h16[jg] = pk16(hjs, ho);
        }
        __syncthreads();   // B: h_{s+1} visible

        const uint4 hu0 = h4p[4 * ks + 0], hu1 = h4p[4 * ks + 1];
        const uint4 hu2 = h4p[4 * ks + 2], hu3 = h4p[4 * ks + 3];
        h2 g[16];
        g[0]  = __builtin_bit_cast(h2, hu0.x); g[1]  = __builtin_bit_cast(h2, hu0.y);
        g[2]  = __builtin_bit_cast(h2, hu0.z); g[3]  = __builtin_bit_cast(h2, hu0.w);
        g[4]  = __builtin_bit_cast(h2, hu1.x); g[5]  = __builtin_bit_cast(h2, hu1.y);
        g[6]  = __builtin_bit_cast(h2, hu1.z); g[7]  = __builtin_bit_cast(h2, hu1.w);
        g[8]  = __builtin_bit_cast(h2, hu2.x); g[9]  = __builtin_bit_cast(h2, hu2.y);
        g[10] = __builtin_bit_cast(h2, hu2.z); g[11] = __builtin_bit_cast(h2, hu2.w);
        g[12] = __builtin_bit_cast(h2, hu3.x); g[13] = __builtin_bit_cast(h2, hu3.y);
        g[14] = __builtin_bit_cast(h2, hu3.z); g[15] = __builtin_bit_cast(h2, hu3.w);

        // ---- FUSED ATT+ACC matvec on h_{s+1}: 64 dot2, 8 chains ----
        float aa0 = 0.0f, ab0 = 0.0f, aa1 = 0.0f, ab1 = 0.0f;
        float ca0 = 0.0f, cb0 = 0.0f, ca1 = 0.0f, cb1 = 0.0f;
#pragma unroll
        for (int i = 0; i < 8; ++i) {
            aa0 = fdot2(wA[0][i],     g[i],     aa0);
            ab0 = fdot2(wA[0][i + 8], g[i + 8], ab0);
            aa1 = fdot2(wA[1][i],     g[i],     aa1);
            ab1 = fdot2(wA[1][i + 8], g[i + 8], ab1);
            ca0 = fdot2(wC[0][i],     g[i],     ca0);
            cb0 = fdot2(wC[0][i + 8], g[i + 8], cb0);
            ca1 = fdot2(wC[1][i],     g[i],     ca1);
            cb1 = fdot2(wC[1][i + 8], g[i + 8], cb1);
        }
        const float asum0 = red4(aa0 + ab0);
        const float asum1 = red4(aa1 + ab1);
        const float csum0 = red4(ca0 + cb0);
        const float csum1 = red4(ca1 + cb1);

        // ONE nonlin: roles 0/1 -> att sigmoid, roles 2/3 -> acc tanh.
        const float zf = (low ? (odd ? asum1 : asum0) : (odd ? csum1 : csum0)) + bFsel;
        const float fres = fmaf(postm,
            __builtin_amdgcn_rcpf(1.0f + __builtin_amdgcn_exp2f(preF * zf)), posta);

        attv = fres;                           // valid roles 0/1
        acs  = fmaf(xe.z, fres, 0.9f * acs);   // valid roles 2/3
    }

    // ---- Output: out[r] = sum_j (h_f + acc_f)[j] * W_out[j] + b_out ----
    float val = (low ? hjs : acs) * wosel;
#pragma unroll
    for (int m = 1; m < 64; m <<= 1) val += __shfl_xor(val, m);
    const int wave = t >> 6, lane = t & 63;
    if (lane == 0) red_s[wave] = val;
    __syncthreads();
    if (t == 0) {
        float o = bout;
#pragma unroll
        for (int w = 0; w < 4; ++w) o += red_s[w];
        out[r] = o;
    }
}

extern "C" void kernel_launch(void* const* d_in, const int* in_sizes, int n_in,
                              void* d_out, int out_size, void* d_ws, size_t ws_size,
                              hipStream_t stream) {
    const float* x     = (const float*)d_in[0];
    const float* W_in  = (const float*)d_in[1];
    const float* b_in  = (const float*)d_in[2];
    const float* W_rec = (const float*)d_in[3];
    const float* b_rec = (const float*)d_in[4];
    const float* tau   = (const float*)d_in[5];
    const float* W_att = (const float*)d_in[6];
    const float* b_att = (const float*)d_in[7];
    const float* W_ev  = (const float*)d_in[8];
    const float* b_ev  = (const float*)d_in[9];
    const float* W_acc = (const float*)d_in[10];
    const float* b_acc = (const float*)d_in[11];
    const float* W_out = (const float*)d_in[12];
    const float* b_out = (const float*)d_in[13];

    float* out    = (float*)d_out;        // [256,1]
    float* out_ew = out + 256;            // [256,2048]

    clnm_kernel<<<256, 256, 0, stream>>>(x, W_in, b_in, W_rec, b_rec, tau,
                                         W_att, b_att, W_ev, b_ev,
                                         W_acc, b_acc, W_out, b_out,
                                         out, out_ew);
}

// Round 11
// 1211.627 us; speedup vs baseline: 1.5047x; 1.0178x over previous
//
#include <hip/hip_runtime.h>

#define DT_C 0.1f
#define LOG2E 1.4426950408889634f

typedef _Float16 h2 __attribute__((ext_vector_type(2)));

__device__ __forceinline__ float sigx(float z) {
    return __builtin_amdgcn_rcpf(1.0f + __builtin_amdgcn_exp2f(-LOG2E * z));
}
__device__ __forceinline__ float tanhx(float z) {
    return fmaf(2.0f, __builtin_amdgcn_rcpf(1.0f + __builtin_amdgcn_exp2f(-2.0f * LOG2E * z)), -1.0f);
}

template <int CTRL>
__device__ __forceinline__ float dpp_add(float v) {
    return v + __int_as_float(__builtin_amdgcn_update_dpp(0, __float_as_int(v), CTRL, 0xF, 0xF, true));
}
// 4-lane butterfly sum (aligned quads): xor1 (0xB1) + xor2 (0x4E).
__device__ __forceinline__ float red4(float v) {
    v = dpp_add<0xB1>(v);
    v = dpp_add<0x4E>(v);
    return v;
}
// quad_perm [1,0,3,2]: partner swap q0<->q1, q2<->q3.
__device__ __forceinline__ float dppswap1(float v) {
    return __int_as_float(__builtin_amdgcn_update_dpp(0, __float_as_int(v), 0xB1, 0xF, 0xF, true));
}
// quad_perm [2,3,0,1]: q0<->q2, q1<->q3.
__device__ __forceinline__ float dppswap2(float v) {
    return __int_as_float(__builtin_amdgcn_update_dpp(0, __float_as_int(v), 0x4E, 0xF, 0xF, true));
}

__device__ __forceinline__ unsigned pk16(float lo, float hi) {
    return __builtin_bit_cast(unsigned, __builtin_amdgcn_cvt_pkrtz(lo, hi));
}
__device__ __forceinline__ float fdot2(h2 a, h2 b, float c) {
    return __builtin_amdgcn_fdot2(a, b, c, false);
}

// B=256, S=2048, I=1, H=128, O=1.
// Grid: 256 blocks (1 row/CU). Block: 512 threads = 8 waves, 2/SIMD.
// R11: WAVE SPECIALIZATION. Waves 0-3 ("main") run the critical path exactly
// like R10's 256-thread kernel, minus the ACC matvec: phase1 REC (32 dot2,
// tanh), phase2 ATT only (32 dot2, pure sigmoid). Waves 4-7 ("acc") own
// W_acc and compute the off-critical-path ACC matvec from h_{s+1} (published
// at barrier B), overlapping main's phase-2 window and filling each other's
// post-barrier ds_read stalls (R10 lesson: 1 wave/SIMD exposes the full
// ~120cyc LDS latency + chain; R9/R10 showed symmetric waves just duplicate
// overhead — asymmetric waves add TLP without adding critical-path work).
// Thread (jg,ks): rows j0=jg, j1=jg+64; packed k-pairs m in [16ks,16ks+16),
// h16[m]={h[m],h[m+64]} half2 (4x ds_read_b128, 2-way alias = free).
__global__ __attribute__((amdgpu_waves_per_eu(2, 2))) __launch_bounds__(512)
void clnm_kernel(const float* __restrict__ x,      // [256,2048]
                 const float* __restrict__ W_in,   // [128,1]
                 const float* __restrict__ b_in,   // [128]
                 const float* __restrict__ W_rec,  // [128,128]
                 const float* __restrict__ b_rec,  // [128]
                 const float* __restrict__ tau,    // [128]
                 const float* __restrict__ W_att,  // [128,128]
                 const float* __restrict__ b_att,  // [128]
                 const float* __restrict__ W_ev,   // [1,2]
                 const float* __restrict__ b_ev,   // [1]
                 const float* __restrict__ W_acc,  // [128,128]
                 const float* __restrict__ b_acc,  // [128]
                 const float* __restrict__ W_out,  // [1,128]
                 const float* __restrict__ b_out,  // [1]
                 float* __restrict__ out,          // [256]
                 float* __restrict__ out_ew)       // [256,2048]
{
    const int t  = threadIdx.x;
    const bool mainw = (t < 256);
    const int tm = mainw ? t : (t - 256);
    const int jg = tm >> 2;       // 0..63
    const int ks = tm & 3;        // 0..3 == role
    const int j0 = jg;
    const int j1 = jg + 64;
    const int r  = blockIdx.x;

    __shared__ __align__(16) float    x_stage[2048];
    __shared__ __align__(16) float4   xe_lds[2048];  // {x_{s+1}, DT(1+ew), 0.1ew, ew}
    __shared__ __align__(16) unsigned h16[64];       // packed {h[m], h[m+64]}
    __shared__ __align__(16) unsigned ha16[64];      // packed hatt
    __shared__ float red_s[8];

    const float wev0 = W_ev[0], wev1 = W_ev[1], bev = b_ev[0], bout = b_out[0];

    ((float4*)x_stage)[t] = ((const float4*)(x + (size_t)r * 2048))[t];
    if (t < 64) h16[t] = 0u;
    __syncthreads();

    // Per-step scalars, 4 steps/thread; out_ew coalesced float4 (exact fp32).
    {
        const int s0 = t * 4;
        const float x0 = x_stage[s0], x1 = x_stage[s0 + 1];
        const float x2 = x_stage[s0 + 2], x3 = x_stage[s0 + 3];
        const float xm1 = (t == 0) ? 0.0f : x_stage[s0 - 1];
        const float x4  = (s0 + 4 < 2048) ? x_stage[s0 + 4] : 0.0f;
        const float e0 = (s0 == 0) ? 0.0f : sigx(fmaf(wev0, x0, fmaf(wev1, xm1, bev)));
        const float e1 = sigx(fmaf(wev0, x1, fmaf(wev1, x0, bev)));
        const float e2 = sigx(fmaf(wev0, x2, fmaf(wev1, x1, bev)));
        const float e3 = sigx(fmaf(wev0, x3, fmaf(wev1, x2, bev)));
        xe_lds[s0 + 0] = make_float4(x1, DT_C * (1.0f + e0), 0.1f * e0, e0);
        xe_lds[s0 + 1] = make_float4(x2, DT_C * (1.0f + e1), 0.1f * e1, e1);
        xe_lds[s0 + 2] = make_float4(x3, DT_C * (1.0f + e2), 0.1f * e2, e2);
        xe_lds[s0 + 3] = make_float4(x4, DT_C * (1.0f + e3), 0.1f * e3, e3);
        ((float4*)(out_ew + (size_t)r * 2048))[t] = make_float4(e0, e1, e2, e3);
    }

    // Weights as half2 pairs {W[row][m], W[row][m+64]}, m = 16ks+i, i<16.
    // main: w1 = W_rec, w2 = W_att.  acc: w1 = W_acc (w2 unused).
    h2 w1[2][16], w2[2][16];
#pragma unroll
    for (int g = 0; g < 2; ++g) {
        const int base = (g ? j1 : j0) * 128 + 16 * ks;
        const float* p1 = mainw ? W_rec : W_acc;
#pragma unroll
        for (int i = 0; i < 16; ++i)
            w1[g][i] = h2{(_Float16)p1[base + i], (_Float16)p1[base + 64 + i]};
        if (mainw) {
#pragma unroll
            for (int i = 0; i < 16; ++i)
                w2[g][i] = h2{(_Float16)W_att[base + i], (_Float16)W_att[base + 64 + i]};
        }
    }

    const bool odd = (ks & 1) != 0;
    const bool low = (ks & 2) == 0;
    const float wosel = odd ? W_out[j1] : W_out[j0];
    // main-only constants (harmless loads on acc waves).
    const float bRsel  = odd ? b_rec[j1] : b_rec[j0];
    const float winsel = odd ? W_in[j1]  : W_in[j0];
    const float binsel = odd ? b_in[j1]  : b_in[j0];
    const float bAsel  = odd ? b_att[j1] : b_att[j0];
    const float tisel  = 1.0f / fminf(fmaxf(odd ? tau[j1] : tau[j0], 0.1f), 10.0f);
    // acc-only constant.
    const float bCsel  = odd ? b_acc[j1] : b_acc[j0];

    float hjs = 0.0f, acs = 0.0f, attv = 0.0f, iccur = 0.0f;
    if (mainw) {
        attv  = sigx(bAsel);                               // att(h_0 = 0)
        iccur = tanhx(fmaf(x_stage[0], winsel, binsel));   // ic for step 0
    }
    __syncthreads();   // xe_lds visible

    const uint4* h4p  = (const uint4*)h16;    // thread reads [4ks .. 4ks+3]
    const uint4* ha4p = (const uint4*)ha16;

    for (int s = 0; s < 2048; ++s) {
        if (mainw) {
            const float hav  = hjs * attv;        // valid on roles 0/1
            const float havo = dppswap1(hav);
            if (ks == 0) ha16[jg] = pk16(hav, havo);
        }
        __syncthreads();   // A: hatt(h_s) visible

        if (mainw) {
            const uint4 au0 = ha4p[4 * ks + 0], au1 = ha4p[4 * ks + 1];
            const uint4 au2 = ha4p[4 * ks + 2], au3 = ha4p[4 * ks + 3];
            const float4 xe = xe_lds[s];   // {x_{s+1}, kk, ewp, ew}
            h2 a[16];
            a[0]  = __builtin_bit_cast(h2, au0.x); a[1]  = __builtin_bit_cast(h2, au0.y);
            a[2]  = __builtin_bit_cast(h2, au0.z); a[3]  = __builtin_bit_cast(h2, au0.w);
            a[4]  = __builtin_bit_cast(h2, au1.x); a[5]  = __builtin_bit_cast(h2, au1.y);
            a[6]  = __builtin_bit_cast(h2, au1.z); a[7]  = __builtin_bit_cast(h2, au1.w);
            a[8]  = __builtin_bit_cast(h2, au2.x); a[9]  = __builtin_bit_cast(h2, au2.y);
            a[10] = __builtin_bit_cast(h2, au2.z); a[11] = __builtin_bit_cast(h2, au2.w);
            a[12] = __builtin_bit_cast(h2, au3.x); a[13] = __builtin_bit_cast(h2, au3.y);
            a[14] = __builtin_bit_cast(h2, au3.z); a[15] = __builtin_bit_cast(h2, au3.w);

            // ---- REC matvec: 32 dot2, 4 chains of depth 8 ----
            float r0a = 0.0f, r0b = 0.0f, r1a = 0.0f, r1b = 0.0f;
#pragma unroll
            for (int i = 0; i < 8; ++i) {
                r0a = fdot2(w1[0][i],     a[i],     r0a);
                r0b = fdot2(w1[0][i + 8], a[i + 8], r0b);
                r1a = fdot2(w1[1][i],     a[i],     r1a);
                r1b = fdot2(w1[1][i + 8], a[i + 8], r1b);
            }
            const float rsum0 = red4(r0a + r0b);
            const float rsum1 = red4(r1a + r1b);

            // ONE tanh: roles 0/1 -> rec(j0/j1); roles 2/3 -> ic_{s+1}(j0/j1).
            const float zsel = low ? ((odd ? rsum1 : rsum0) + bRsel)
                                   : fmaf(xe.x, winsel, binsel);
            const float tres = tanhx(zsel);
            const float icn  = dppswap2(tres);

            // h update (valid on roles 0/1): h += kk*ti * ((ic+rec) - h)
            hjs = fmaf(xe.y * tisel, (iccur + tres) - hjs, hjs);
            iccur = icn;
            const float ho = dppswap1(hjs);
            if (ks == 0) h16[jg] = pk16(hjs, ho);
        }
        __syncthreads();   // B: h_{s+1} visible

        const uint4 hu0 = h4p[4 * ks + 0], hu1 = h4p[4 * ks + 1];
        const uint4 hu2 = h4p[4 * ks + 2], hu3 = h4p[4 * ks + 3];
        h2 g[16];
        g[0]  = __builtin_bit_cast(h2, hu0.x); g[1]  = __builtin_bit_cast(h2, hu0.y);
        g[2]  = __builtin_bit_cast(h2, hu0.z); g[3]  = __builtin_bit_cast(h2, hu0.w);
        g[4]  = __builtin_bit_cast(h2, hu1.x); g[5]  = __builtin_bit_cast(h2, hu1.y);
        g[6]  = __builtin_bit_cast(h2, hu1.z); g[7]  = __builtin_bit_cast(h2, hu1.w);
        g[8]  = __builtin_bit_cast(h2, hu2.x); g[9]  = __builtin_bit_cast(h2, hu2.y);
        g[10] = __builtin_bit_cast(h2, hu2.z); g[11] = __builtin_bit_cast(h2, hu2.w);
        g[12] = __builtin_bit_cast(h2, hu3.x); g[13] = __builtin_bit_cast(h2, hu3.y);
        g[14] = __builtin_bit_cast(h2, hu3.z); g[15] = __builtin_bit_cast(h2, hu3.w);

        if (mainw) {
            // ---- ATT matvec on h_{s+1}: 32 dot2, pure sigmoid ----
            float aa0 = 0.0f, ab0 = 0.0f, aa1 = 0.0f, ab1 = 0.0f;
#pragma unroll
            for (int i = 0; i < 8; ++i) {
                aa0 = fdot2(w2[0][i],     g[i],     aa0);
                ab0 = fdot2(w2[0][i + 8], g[i + 8], ab0);
                aa1 = fdot2(w2[1][i],     g[i],     aa1);
                ab1 = fdot2(w2[1][i + 8], g[i + 8], ab1);
            }
            const float asum0 = red4(aa0 + ab0);
            const float asum1 = red4(aa1 + ab1);
            attv = sigx((odd ? asum1 : asum0) + bAsel);
        } else {
            // ---- ACC matvec on h_{s+1}: 32 dot2, tanh, private acc ----
            const float4 xe = xe_lds[s];   // need .z = 0.1*ew(s)
            float ca0 = 0.0f, cb0 = 0.0f, ca1 = 0.0f, cb1 = 0.0f;
#pragma unroll
            for (int i = 0; i < 8; ++i) {
                ca0 = fdot2(w1[0][i],     g[i],     ca0);
                cb0 = fdot2(w1[0][i + 8], g[i + 8], cb0);
                ca1 = fdot2(w1[1][i],     g[i],     ca1);
                cb1 = fdot2(w1[1][i + 8], g[i + 8], cb1);
            }
            const float csum0 = red4(ca0 + cb0);
            const float csum1 = red4(ca1 + cb1);
            const float tc = tanhx((odd ? csum1 : csum0) + bCsel);
            acs = fmaf(xe.z, tc, 0.9f * acs);
        }
    }

    // ---- Output: out[r] = sum_j (h_f + acc_f)[j] * W_out[j] + b_out ----
    // h contributions on main roles 0/1; acc contributions on acc roles 0/1.
    float val = low ? (mainw ? hjs : acs) * wosel : 0.0f;
#pragma unroll
    for (int m = 1; m < 64; m <<= 1) val += __shfl_xor(val, m);
    const int wave = t >> 6, lane = t & 63;
    if (lane == 0) red_s[wave] = val;
    __syncthreads();
    if (t == 0) {
        float o = bout;
#pragma unroll
        for (int w = 0; w < 8; ++w) o += red_s[w];
        out[r] = o;
    }
}

extern "C" void kernel_launch(void* const* d_in, const int* in_sizes, int n_in,
                              void* d_out, int out_size, void* d_ws, size_t ws_size,
                              hipStream_t stream) {
    const float* x     = (const float*)d_in[0];
    const float* W_in  = (const float*)d_in[1];
    const float* b_in  = (const float*)d_in[2];
    const float* W_rec = (const float*)d_in[3];
    const float* b_rec = (const float*)d_in[4];
    const float* tau   = (const float*)d_in[5];
    const float* W_att = (const float*)d_in[6];
    const float* b_att = (const float*)d_in[7];
    const float* W_ev  = (const float*)d_in[8];
    const float* b_ev  = (const float*)d_in[9];
    const float* W_acc = (const float*)d_in[10];
    const float* b_acc = (const float*)d_in[11];
    const float* W_out = (const float*)d_in[12];
    const float* b_out = (const float*)d_in[13];

    float* out    = (float*)d_out;        // [256,1]
    float* out_ew = out + 256;            // [256,2048]

    clnm_kernel<<<256, 512, 0, stream>>>(x, W_in, b_in, W_rec, b_rec, tau,
                                         W_att, b_att, W_ev, b_ev,
                                         W_acc, b_acc, W_out, b_out,
                                         out, out_ew);
}

// Round 12
// 1115.108 us; speedup vs baseline: 1.6349x; 1.0866x over previous
//
#include <hip/hip_runtime.h>

#define DT_C 0.1f
#define LOG2E 1.4426950408889634f
#define S_ACC 1792   // 0.9^256 * 0.1 < 2e-13: acc contributions before this are invisible at fp32

typedef _Float16 h2 __attribute__((ext_vector_type(2)));

__device__ __forceinline__ float sigx(float z) {
    return __builtin_amdgcn_rcpf(1.0f + __builtin_amdgcn_exp2f(-LOG2E * z));
}
__device__ __forceinline__ float tanhx(float z) {
    return fmaf(2.0f, __builtin_amdgcn_rcpf(1.0f + __builtin_amdgcn_exp2f(-2.0f * LOG2E * z)), -1.0f);
}

template <int CTRL>
__device__ __forceinline__ float dpp_add(float v) {
    return v + __int_as_float(__builtin_amdgcn_update_dpp(0, __float_as_int(v), CTRL, 0xF, 0xF, true));
}
// 4-lane butterfly sum (aligned quads): xor1 (0xB1) + xor2 (0x4E).
__device__ __forceinline__ float red4(float v) {
    v = dpp_add<0xB1>(v);
    v = dpp_add<0x4E>(v);
    return v;
}
// quad_perm [1,0,3,2]: partner swap q0<->q1, q2<->q3.
__device__ __forceinline__ float dppswap1(float v) {
    return __int_as_float(__builtin_amdgcn_update_dpp(0, __float_as_int(v), 0xB1, 0xF, 0xF, true));
}
// quad_perm [2,3,0,1]: q0<->q2, q1<->q3.
__device__ __forceinline__ float dppswap2(float v) {
    return __int_as_float(__builtin_amdgcn_update_dpp(0, __float_as_int(v), 0x4E, 0xF, 0xF, true));
}

__device__ __forceinline__ unsigned pk16(float lo, float hi) {
    return __builtin_bit_cast(unsigned, __builtin_amdgcn_cvt_pkrtz(lo, hi));
}
__device__ __forceinline__ float fdot2(h2 a, h2 b, float c) {
    return __builtin_amdgcn_fdot2(a, b, c, false);
}

// B=256, S=2048, I=1, H=128, O=1.
// Grid: 256 blocks (1 row/CU). Block: 256 threads = 4 waves = 1 wave/SIMD.
// R12: the wall is stall-dominated (R11: -180cy issue -> -1.7% wall). Attack
// the dependent chain + fixed overhead only:
//  (1) LATE-ACC: acc contribution of step t is weighted 0.1*0.9^(2047-t);
//      for t<1792 that is <2e-13 (below fp32 noise) -> ACC matvec runs only
//      for the last 256 steps. Helper waves deleted.
//  (2) Depth-4 dot2 chains (4 accumulators/row) to cut dep latency per tick.
// Layout (verified R10): t=jg*4+ks, quad roles; rows j0=jg, j1=jg+64; packed
// k-pairs m in [16ks,16ks+16), h16[m]={h[m],h[m+64]} half2; 4x ds_read_b128
// per exchange (2-way bank alias = free); v_dot2_f32_f16 matvecs; fp32 state.
__global__ __attribute__((amdgpu_waves_per_eu(1, 1))) __launch_bounds__(256)
void clnm_kernel(const float* __restrict__ x,      // [256,2048]
                 const float* __restrict__ W_in,   // [128,1]
                 const float* __restrict__ b_in,   // [128]
                 const float* __restrict__ W_rec,  // [128,128]
                 const float* __restrict__ b_rec,  // [128]
                 const float* __restrict__ tau,    // [128]
                 const float* __restrict__ W_att,  // [128,128]
                 const float* __restrict__ b_att,  // [128]
                 const float* __restrict__ W_ev,   // [1,2]
                 const float* __restrict__ b_ev,   // [1]
                 const float* __restrict__ W_acc,  // [128,128]
                 const float* __restrict__ b_acc,  // [128]
                 const float* __restrict__ W_out,  // [1,128]
                 const float* __restrict__ b_out,  // [1]
                 float* __restrict__ out,          // [256]
                 float* __restrict__ out_ew)       // [256,2048]
{
    const int t  = threadIdx.x;
    const int jg = t >> 2;        // 0..63
    const int ks = t & 3;         // 0..3 == role
    const int j0 = jg;
    const int j1 = jg + 64;
    const int r  = blockIdx.x;

    __shared__ __align__(16) float    x_stage[2048];
    __shared__ __align__(16) float4   xe_lds[2048];  // {x_{s+1}, DT(1+ew), 0.1ew, ew}
    __shared__ __align__(16) unsigned h16[64];       // packed {h[m], h[m+64]}
    __shared__ __align__(16) unsigned ha16[64];      // packed hatt
    __shared__ float red_s[4];

    const float wev0 = W_ev[0], wev1 = W_ev[1], bev = b_ev[0], bout = b_out[0];

    ((float4*)x_stage)[t]       = ((const float4*)(x + (size_t)r * 2048))[t];
    ((float4*)x_stage)[t + 256] = ((const float4*)(x + (size_t)r * 2048))[t + 256];
    if (t < 64) h16[t] = 0u;
    __syncthreads();

    // Per-step scalars, 8 steps/thread; out_ew coalesced float4 (exact fp32).
    {
        const int s0 = t * 8;
        float xv[9];
#pragma unroll
        for (int i = 0; i < 8; ++i) xv[i] = x_stage[s0 + i];
        xv[8] = (s0 + 8 < 2048) ? x_stage[s0 + 8] : 0.0f;
        const float xm1 = (t == 0) ? 0.0f : x_stage[s0 - 1];
        float e[8];
        e[0] = (s0 == 0) ? 0.0f : sigx(fmaf(wev0, xv[0], fmaf(wev1, xm1, bev)));
#pragma unroll
        for (int i = 1; i < 8; ++i)
            e[i] = sigx(fmaf(wev0, xv[i], fmaf(wev1, xv[i - 1], bev)));
#pragma unroll
        for (int i = 0; i < 8; ++i)
            xe_lds[s0 + i] = make_float4(xv[i + 1], DT_C * (1.0f + e[i]), 0.1f * e[i], e[i]);
        ((float4*)(out_ew + (size_t)r * 2048))[2 * t]     = make_float4(e[0], e[1], e[2], e[3]);
        ((float4*)(out_ew + (size_t)r * 2048))[2 * t + 1] = make_float4(e[4], e[5], e[6], e[7]);
    }

    // Weights as half2 pairs {W[row][m], W[row][m+64]}, m = 16ks+i, i<16.
    h2 wA[2][16], wR[2][16], wC[2][16];
#pragma unroll
    for (int g = 0; g < 2; ++g) {
        const int base = (g ? j1 : j0) * 128 + 16 * ks;
#pragma unroll
        for (int i = 0; i < 16; ++i) {
            wA[g][i] = h2{(_Float16)W_att[base + i], (_Float16)W_att[base + 64 + i]};
            wR[g][i] = h2{(_Float16)W_rec[base + i], (_Float16)W_rec[base + 64 + i]};
            wC[g][i] = h2{(_Float16)W_acc[base + i], (_Float16)W_acc[base + 64 + i]};
        }
    }

    // Lane roles (exact, ks==role): 0: rec/att j0, 1: rec/att j1,
    // 2: ic/acc j0, 3: ic/acc j1.
    const bool odd = (ks & 1) != 0;
    const bool low = (ks & 2) == 0;
    const float bRsel  = odd ? b_rec[j1] : b_rec[j0];
    const float winsel = odd ? W_in[j1]  : W_in[j0];
    const float binsel = odd ? b_in[j1]  : b_in[j0];
    const float bFsel  = low ? (odd ? b_att[j1] : b_att[j0])
                             : (odd ? b_acc[j1] : b_acc[j0]);
    const float bAsel  = odd ? b_att[j1] : b_att[j0];
    const float preF   = low ? -LOG2E : -2.0f * LOG2E;   // sigmoid vs tanh
    const float postm  = low ? 1.0f : 2.0f;
    const float posta  = low ? 0.0f : -1.0f;
    const float tisel  = 1.0f / fminf(fmaxf(odd ? tau[j1] : tau[j0], 0.1f), 10.0f);
    const float wosel  = odd ? W_out[j1] : W_out[j0];

    __syncthreads();   // h16 zeros + xe_lds visible

    float hjs = 0.0f, acs = 0.0f;
    float attv = sigx(bAsel);                              // att(h_0=0), roles 0/1
    float iccur = tanhx(fmaf(x_stage[0], winsel, binsel)); // ic for step 0

    const uint4* h4p  = (const uint4*)h16;    // thread reads [4ks .. 4ks+3]
    const uint4* ha4p = (const uint4*)ha16;

    for (int s = 0; s < 2048; ++s) {
        // Publish hatt (packed): ks==0 packs own (j0) + partner's (j1).
        {
            const float hav  = hjs * attv;        // valid on roles 0/1
            const float havo = dppswap1(hav);
            if (ks == 0) ha16[jg] = pk16(hav, havo);
        }
        __syncthreads();   // A: hatt(h_s) visible

        const uint4 au0 = ha4p[4 * ks + 0], au1 = ha4p[4 * ks + 1];
        const uint4 au2 = ha4p[4 * ks + 2], au3 = ha4p[4 * ks + 3];
        const float4 xe = xe_lds[s];   // {x_{s+1}, kk, ewp, ew}
        h2 a[16];
        a[0]  = __builtin_bit_cast(h2, au0.x); a[1]  = __builtin_bit_cast(h2, au0.y);
        a[2]  = __builtin_bit_cast(h2, au0.z); a[3]  = __builtin_bit_cast(h2, au0.w);
        a[4]  = __builtin_bit_cast(h2, au1.x); a[5]  = __builtin_bit_cast(h2, au1.y);
        a[6]  = __builtin_bit_cast(h2, au1.z); a[7]  = __builtin_bit_cast(h2, au1.w);
        a[8]  = __builtin_bit_cast(h2, au2.x); a[9]  = __builtin_bit_cast(h2, au2.y);
        a[10] = __builtin_bit_cast(h2, au2.z); a[11] = __builtin_bit_cast(h2, au2.w);
        a[12] = __builtin_bit_cast(h2, au3.x); a[13] = __builtin_bit_cast(h2, au3.y);
        a[14] = __builtin_bit_cast(h2, au3.z); a[15] = __builtin_bit_cast(h2, au3.w);

        // ---- REC matvec: 32 dot2, 8 chains of depth 4 (short dep chain) ----
        float p0[4] = {0.f, 0.f, 0.f, 0.f}, p1[4] = {0.f, 0.f, 0.f, 0.f};
#pragma unroll
        for (int c = 0; c < 4; ++c)
#pragma unroll
            for (int i = 0; i < 4; ++i) {
                p0[c] = fdot2(wR[0][4 * c + i], a[4 * c + i], p0[c]);
                p1[c] = fdot2(wR[1][4 * c + i], a[4 * c + i], p1[c]);
            }
        const float rsum0 = red4((p0[0] + p0[1]) + (p0[2] + p0[3]));
        const float rsum1 = red4((p1[0] + p1[1]) + (p1[2] + p1[3]));

        // ONE tanh: roles 0/1 -> rec(j0/j1); roles 2/3 -> ic_{s+1}(j0/j1).
        const float zsel = low ? ((odd ? rsum1 : rsum0) + bRsel)
                               : fmaf(xe.x, winsel, binsel);
        const float tres = tanhx(zsel);
        const float icn  = dppswap2(tres);

        // h update (valid on roles 0/1): h += kk*ti * ((ic+rec) - h)
        hjs = fmaf(xe.y * tisel, (iccur + tres) - hjs, hjs);
        iccur = icn;
        {
            const float ho = dppswap1(hjs);
            if (ks == 0) h16[jg] = pk16(hjs, ho);
        }
        __syncthreads();   // B: h_{s+1} visible

        const uint4 hu0 = h4p[4 * ks + 0], hu1 = h4p[4 * ks + 1];
        const uint4 hu2 = h4p[4 * ks + 2], hu3 = h4p[4 * ks + 3];
        h2 g[16];
        g[0]  = __builtin_bit_cast(h2, hu0.x); g[1]  = __builtin_bit_cast(h2, hu0.y);
        g[2]  = __builtin_bit_cast(h2, hu0.z); g[3]  = __builtin_bit_cast(h2, hu0.w);
        g[4]  = __builtin_bit_cast(h2, hu1.x); g[5]  = __builtin_bit_cast(h2, hu1.y);
        g[6]  = __builtin_bit_cast(h2, hu1.z); g[7]  = __builtin_bit_cast(h2, hu1.w);
        g[8]  = __builtin_bit_cast(h2, hu2.x); g[9]  = __builtin_bit_cast(h2, hu2.y);
        g[10] = __builtin_bit_cast(h2, hu2.z); g[11] = __builtin_bit_cast(h2, hu2.w);
        g[12] = __builtin_bit_cast(h2, hu3.x); g[13] = __builtin_bit_cast(h2, hu3.y);
        g[14] = __builtin_bit_cast(h2, hu3.z); g[15] = __builtin_bit_cast(h2, hu3.w);

        // ---- ATT matvec on h_{s+1}: 32 dot2, 8 chains of depth 4 ----
        float q0[4] = {0.f, 0.f, 0.f, 0.f}, q1[4] = {0.f, 0.f, 0.f, 0.f};
#pragma unroll
        for (int c = 0; c < 4; ++c)
#pragma unroll
            for (int i = 0; i < 4; ++i) {
                q0[c] = fdot2(wA[0][4 * c + i], g[4 * c + i], q0[c]);
                q1[c] = fdot2(wA[1][4 * c + i], g[4 * c + i], q1[c]);
            }
        const float asum0 = red4((q0[0] + q0[1]) + (q0[2] + q0[3]));
        const float asum1 = red4((q1[0] + q1[1]) + (q1[2] + q1[3]));

        if (s < S_ACC) {
            // Early steps: acc contribution < 2e-13 -> skip ACC entirely.
            attv = sigx((odd ? asum1 : asum0) + bAsel);
        } else {
            // Late steps: fused ACC matvec + shared role nonlin (R10 pattern).
            float c0[4] = {0.f, 0.f, 0.f, 0.f}, c1[4] = {0.f, 0.f, 0.f, 0.f};
#pragma unroll
            for (int c = 0; c < 4; ++c)
#pragma unroll
                for (int i = 0; i < 4; ++i) {
                    c0[c] = fdot2(wC[0][4 * c + i], g[4 * c + i], c0[c]);
                    c1[c] = fdot2(wC[1][4 * c + i], g[4 * c + i], c1[c]);
                }
            const float csum0 = red4((c0[0] + c0[1]) + (c0[2] + c0[3]));
            const float csum1 = red4((c1[0] + c1[1]) + (c1[2] + c1[3]));
            // ONE nonlin: roles 0/1 -> att sigmoid, roles 2/3 -> acc tanh.
            const float zf = (low ? (odd ? asum1 : asum0) : (odd ? csum1 : csum0)) + bFsel;
            const float fres = fmaf(postm,
                __builtin_amdgcn_rcpf(1.0f + __builtin_amdgcn_exp2f(preF * zf)), posta);
            attv = fres;                           // valid roles 0/1
            acs  = fmaf(xe.z, fres, 0.9f * acs);   // valid roles 2/3
        }
    }

    // ---- Output: out[r] = sum_j (h_f + acc_f)[j] * W_out[j] + b_out ----
    float val = (low ? hjs : acs) * wosel;
#pragma unroll
    for (int m = 1; m < 64; m <<= 1) val += __shfl_xor(val, m);
    const int wave = t >> 6, lane = t & 63;
    if (lane == 0) red_s[wave] = val;
    __syncthreads();
    if (t == 0) {
        float o = bout;
#pragma unroll
        for (int w = 0; w < 4; ++w) o += red_s[w];
        out[r] = o;
    }
}

extern "C" void kernel_launch(void* const* d_in, const int* in_sizes, int n_in,
                              void* d_out, int out_size, void* d_ws, size_t ws_size,
                              hipStream_t stream) {
    const float* x     = (const float*)d_in[0];
    const float* W_in  = (const float*)d_in[1];
    const float* b_in  = (const float*)d_in[2];
    const float* W_rec = (const float*)d_in[3];
    const float* b_rec = (const float*)d_in[4];
    const float* tau   = (const float*)d_in[5];
    const float* W_att = (const float*)d_in[6];
    const float* b_att = (const float*)d_in[7];
    const float* W_ev  = (const float*)d_in[8];
    const float* b_ev  = (const float*)d_in[9];
    const float* W_acc = (const float*)d_in[10];
    const float* b_acc = (const float*)d_in[11];
    const float* W_out = (const float*)d_in[12];
    const float* b_out = (const float*)d_in[13];

    float* out    = (float*)d_out;        // [256,1]
    float* out_ew = out + 256;            // [256,2048]

    clnm_kernel<<<256, 256, 0, stream>>>(x, W_in, b_in, W_rec, b_rec, tau,
                                         W_att, b_att, W_ev, b_ev,
                                         W_acc, b_acc, W_out, b_out,
                                         out, out_ew);
}

// Round 13
// 1066.638 us; speedup vs baseline: 1.7092x; 1.0454x over previous
//
#include <hip/hip_runtime.h>

#define DT_C 0.1f
#define LOG2E 1.4426950408889634f
#define S_ACC 1920   // drop acc for t<1920: |err| <= 0.9^128 ~ 1.4e-6 << 1.8e-2 threshold

typedef _Float16 h2 __attribute__((ext_vector_type(2)));

__device__ __forceinline__ float sigx(float z) {
    return __builtin_amdgcn_rcpf(1.0f + __builtin_amdgcn_exp2f(-LOG2E * z));
}
__device__ __forceinline__ float tanhx(float z) {
    return fmaf(2.0f, __builtin_amdgcn_rcpf(1.0f + __builtin_amdgcn_exp2f(-2.0f * LOG2E * z)), -1.0f);
}

template <int CTRL>
__device__ __forceinline__ float dpp_add(float v) {
    return v + __int_as_float(__builtin_amdgcn_update_dpp(0, __float_as_int(v), CTRL, 0xF, 0xF, true));
}
// 4-lane butterfly sum (aligned quads): xor1 (0xB1) + xor2 (0x4E).
__device__ __forceinline__ float red4(float v) {
    v = dpp_add<0xB1>(v);
    v = dpp_add<0x4E>(v);
    return v;
}
__device__ __forceinline__ float fdot2(h2 a, h2 b, float c) {
    return __builtin_amdgcn_fdot2(a, b, c, false);
}

// B=256, S=2048, I=1, H=128, O=1.
// Grid: 256 blocks (1 row/CU). Block: 256 threads = 4 waves = 1 wave/SIMD.
// Structure (R10/R12, at its latency floor pieces): 2 j->k exchanges per step
// (hatt then h) — irreducible for two serial distributed matvecs. R13 shaves
// the dependent chain: dual b16 publishes (no swap/pack), folded exp2 args
// (bias pre-multiplied), h-update as single post-tanh fma (decay+ic precomputed
// in the DS-wait window), per-lane own-row ic (no cross-lane ic handoff).
// Layout: t=jg*4+ks; rows j0=jg, j1=jg+64; packed k-pairs m in [16ks,16ks+16),
// h16[m]={h[m],h[m+64]} half2; 4x ds_read_b128/exchange (2-way alias = free);
// v_dot2_f32_f16 matvecs; fp32 state and nonlinearities.
__global__ __attribute__((amdgpu_waves_per_eu(1, 1))) __launch_bounds__(256)
void clnm_kernel(const float* __restrict__ x,      // [256,2048]
                 const float* __restrict__ W_in,   // [128,1]
                 const float* __restrict__ b_in,   // [128]
                 const float* __restrict__ W_rec,  // [128,128]
                 const float* __restrict__ b_rec,  // [128]
                 const float* __restrict__ tau,    // [128]
                 const float* __restrict__ W_att,  // [128,128]
                 const float* __restrict__ b_att,  // [128]
                 const float* __restrict__ W_ev,   // [1,2]
                 const float* __restrict__ b_ev,   // [1]
                 const float* __restrict__ W_acc,  // [128,128]
                 const float* __restrict__ b_acc,  // [128]
                 const float* __restrict__ W_out,  // [1,128]
                 const float* __restrict__ b_out,  // [1]
                 float* __restrict__ out,          // [256]
                 float* __restrict__ out_ew)       // [256,2048]
{
    const int t  = threadIdx.x;
    const int jg = t >> 2;        // 0..63
    const int ks = t & 3;         // 0..3 == role
    const int j0 = jg;
    const int j1 = jg + 64;
    const int r  = blockIdx.x;

    __shared__ __align__(16) float    x_stage[2048];
    __shared__ __align__(16) float4   xe_lds[2048];  // {x_{s+1}, DT(1+ew), 0.1ew, ew}
    __shared__ __align__(16) unsigned h16[64];       // packed {h[m], h[m+64]} f16
    __shared__ __align__(16) unsigned ha16[64];      // packed hatt f16
    __shared__ float red_s[4];

    const float wev0 = W_ev[0], wev1 = W_ev[1], bev = b_ev[0], bout = b_out[0];

    ((float4*)x_stage)[t]       = ((const float4*)(x + (size_t)r * 2048))[t];
    ((float4*)x_stage)[t + 256] = ((const float4*)(x + (size_t)r * 2048))[t + 256];
    if (t < 64) { h16[t] = 0u; ha16[t] = 0u; }   // h_0 = 0, hatt_0 = 0
    __syncthreads();

    // Per-step scalars, 8 steps/thread; out_ew coalesced float4 (exact fp32).
    {
        const int s0 = t * 8;
        float xv[9];
#pragma unroll
        for (int i = 0; i < 8; ++i) xv[i] = x_stage[s0 + i];
        xv[8] = (s0 + 8 < 2048) ? x_stage[s0 + 8] : 0.0f;
        const float xm1 = (t == 0) ? 0.0f : x_stage[s0 - 1];
        float e[8];
        e[0] = (s0 == 0) ? 0.0f : sigx(fmaf(wev0, xv[0], fmaf(wev1, xm1, bev)));
#pragma unroll
        for (int i = 1; i < 8; ++i)
            e[i] = sigx(fmaf(wev0, xv[i], fmaf(wev1, xv[i - 1], bev)));
#pragma unroll
        for (int i = 0; i < 8; ++i)
            xe_lds[s0 + i] = make_float4(xv[i + 1], DT_C * (1.0f + e[i]), 0.1f * e[i], e[i]);
        ((float4*)(out_ew + (size_t)r * 2048))[2 * t]     = make_float4(e[0], e[1], e[2], e[3]);
        ((float4*)(out_ew + (size_t)r * 2048))[2 * t + 1] = make_float4(e[4], e[5], e[6], e[7]);
    }

    // Weights as half2 pairs {W[row][m], W[row][m+64]}, m = 16ks+i, i<16.
    h2 wA[2][16], wR[2][16], wC[2][16];
#pragma unroll
    for (int g = 0; g < 2; ++g) {
        const int base = (g ? j1 : j0) * 128 + 16 * ks;
#pragma unroll
        for (int i = 0; i < 16; ++i) {
            wA[g][i] = h2{(_Float16)W_att[base + i], (_Float16)W_att[base + 64 + i]};
            wR[g][i] = h2{(_Float16)W_rec[base + i], (_Float16)W_rec[base + 64 + i]};
            wC[g][i] = h2{(_Float16)W_acc[base + i], (_Float16)W_acc[base + 64 + i]};
        }
    }

    // Lane roles: 0: rec/att j0, 1: rec/att j1, 2: acc j0, 3: acc j1.
    // Every lane computes its OWN row's ic (winsel/binsel row-correct for all).
    const bool odd = (ks & 1) != 0;
    const bool low = (ks & 2) == 0;
    const float m2 = -2.0f * LOG2E;                       // tanh exp-arg scale
    const float bRsel  = odd ? b_rec[j1] : b_rec[j0];
    const float winsel = odd ? W_in[j1]  : W_in[j0];
    const float binsel = odd ? b_in[j1]  : b_in[j0];
    const float bR2m   = m2 * bRsel;                      // folded rec bias
    const float m2win  = m2 * winsel, m2bin = m2 * binsel; // folded ic args
    const float bAsel  = odd ? b_att[j1] : b_att[j0];
    const float bA1m   = -LOG2E * bAsel;                  // folded att bias
    const float bFsel  = low ? bAsel : (odd ? b_acc[j1] : b_acc[j0]);
    const float preF   = low ? -LOG2E : m2;               // sigmoid vs tanh
    const float preFb  = preF * bFsel;
    const float postm  = low ? 1.0f : 2.0f;
    const float posta  = low ? 0.0f : -1.0f;
    const float tisel  = 1.0f / fminf(fmaxf(odd ? tau[j1] : tau[j0], 0.1f), 10.0f);
    const float wosel  = odd ? W_out[j1] : W_out[j0];

    __syncthreads();   // h16/ha16 zeros + xe_lds visible

    float hjs = 0.0f, acs = 0.0f;
    float iccur = tanhx(fmaf(x_stage[0], winsel, binsel));  // ic for step 0, own row

    const uint4* h4p  = (const uint4*)h16;    // thread reads [4ks .. 4ks+3]
    const uint4* ha4p = (const uint4*)ha16;
    _Float16* h16h  = (_Float16*)h16;         // dual-b16 publish
    _Float16* ha16h = (_Float16*)ha16;

    for (int s = 0; s < 2048; ++s) {
        __syncthreads();   // A: hatt(h_s) visible (s=0: zeros)

        const uint4 au0 = ha4p[4 * ks + 0], au1 = ha4p[4 * ks + 1];
        const uint4 au2 = ha4p[4 * ks + 2], au3 = ha4p[4 * ks + 3];
        const float4 xe = xe_lds[s];   // {x_{s+1}, kk, ewp, ew}
        h2 a[16];
        a[0]  = __builtin_bit_cast(h2, au0.x); a[1]  = __builtin_bit_cast(h2, au0.y);
        a[2]  = __builtin_bit_cast(h2, au0.z); a[3]  = __builtin_bit_cast(h2, au0.w);
        a[4]  = __builtin_bit_cast(h2, au1.x); a[5]  = __builtin_bit_cast(h2, au1.y);
        a[6]  = __builtin_bit_cast(h2, au1.z); a[7]  = __builtin_bit_cast(h2, au1.w);
        a[8]  = __builtin_bit_cast(h2, au2.x); a[9]  = __builtin_bit_cast(h2, au2.y);
        a[10] = __builtin_bit_cast(h2, au2.z); a[11] = __builtin_bit_cast(h2, au2.w);
        a[12] = __builtin_bit_cast(h2, au3.x); a[13] = __builtin_bit_cast(h2, au3.y);
        a[14] = __builtin_bit_cast(h2, au3.z); a[15] = __builtin_bit_cast(h2, au3.w);

        // Off-chain precompute in the DS-wait window:
        const float kkti  = xe.y * tisel;
        const float hpre2 = fmaf(kkti, iccur, fmaf(-kkti, hjs, hjs)); // h(1-kkti)+kkti*ic
        const float icn   = fmaf(2.0f, __builtin_amdgcn_rcpf(
                              1.0f + __builtin_amdgcn_exp2f(fmaf(m2win, xe.x, m2bin))), -1.0f);

        // ---- REC matvec: 32 dot2, 8 chains of depth 4 ----
        float p0[4] = {0.f, 0.f, 0.f, 0.f}, p1[4] = {0.f, 0.f, 0.f, 0.f};
#pragma unroll
        for (int c = 0; c < 4; ++c)
#pragma unroll
            for (int i = 0; i < 4; ++i) {
                p0[c] = fdot2(wR[0][4 * c + i], a[4 * c + i], p0[c]);
                p1[c] = fdot2(wR[1][4 * c + i], a[4 * c + i], p1[c]);
            }
        const float rsum0 = red4((p0[0] + p0[1]) + (p0[2] + p0[3]));
        const float rsum1 = red4((p1[0] + p1[1]) + (p1[2] + p1[3]));

        // Chain: cndmask -> fma -> exp2 -> add -> rcp -> fma -> fma -> cvt -> write
        const float rsumsel = odd ? rsum1 : rsum0;
        const float tres = fmaf(2.0f, __builtin_amdgcn_rcpf(
                             1.0f + __builtin_amdgcn_exp2f(fmaf(m2, rsumsel, bR2m))), -1.0f);
        hjs = fmaf(kkti, tres, hpre2);   // valid on roles 0/1
        iccur = icn;
        if (ks < 2) h16h[2 * jg + ks] = (_Float16)hjs;
        __syncthreads();   // B: h_{s+1} visible

        const uint4 hu0 = h4p[4 * ks + 0], hu1 = h4p[4 * ks + 1];
        const uint4 hu2 = h4p[4 * ks + 2], hu3 = h4p[4 * ks + 3];
        h2 g[16];
        g[0]  = __builtin_bit_cast(h2, hu0.x); g[1]  = __builtin_bit_cast(h2, hu0.y);
        g[2]  = __builtin_bit_cast(h2, hu0.z); g[3]  = __builtin_bit_cast(h2, hu0.w);
        g[4]  = __builtin_bit_cast(h2, hu1.x); g[5]  = __builtin_bit_cast(h2, hu1.y);
        g[6]  = __builtin_bit_cast(h2, hu1.z); g[7]  = __builtin_bit_cast(h2, hu1.w);
        g[8]  = __builtin_bit_cast(h2, hu2.x); g[9]  = __builtin_bit_cast(h2, hu2.y);
        g[10] = __builtin_bit_cast(h2, hu2.z); g[11] = __builtin_bit_cast(h2, hu2.w);
        g[12] = __builtin_bit_cast(h2, hu3.x); g[13] = __builtin_bit_cast(h2, hu3.y);
        g[14] = __builtin_bit_cast(h2, hu3.z); g[15] = __builtin_bit_cast(h2, hu3.w);

        // ---- ATT matvec on h_{s+1}: 32 dot2, 8 chains of depth 4 ----
        float q0[4] = {0.f, 0.f, 0.f, 0.f}, q1[4] = {0.f, 0.f, 0.f, 0.f};
#pragma unroll
        for (int c = 0; c < 4; ++c)
#pragma unroll
            for (int i = 0; i < 4; ++i) {
                q0[c] = fdot2(wA[0][4 * c + i], g[4 * c + i], q0[c]);
                q1[c] = fdot2(wA[1][4 * c + i], g[4 * c + i], q1[c]);
            }
        const float asum0 = red4((q0[0] + q0[1]) + (q0[2] + q0[3]));
        const float asum1 = red4((q1[0] + q1[1]) + (q1[2] + q1[3]));

        if (s < S_ACC) {
            // Chain: cndmask -> fma -> exp2 -> add -> rcp -> mul -> cvt -> write
            const float asumsel = odd ? asum1 : asum0;
            const float sg = __builtin_amdgcn_rcpf(
                1.0f + __builtin_amdgcn_exp2f(fmaf(-LOG2E, asumsel, bA1m)));
            const float hav = hjs * sg;            // hatt_{s+1}, roles 0/1
            if (ks < 2) ha16h[2 * jg + ks] = (_Float16)hav;
        } else {
            // Last 128 steps: fused ACC matvec + role nonlin.
            float c0[4] = {0.f, 0.f, 0.f, 0.f}, c1[4] = {0.f, 0.f, 0.f, 0.f};
#pragma unroll
            for (int c = 0; c < 4; ++c)
#pragma unroll
                for (int i = 0; i < 4; ++i) {
                    c0[c] = fdot2(wC[0][4 * c + i], g[4 * c + i], c0[c]);
                    c1[c] = fdot2(wC[1][4 * c + i], g[4 * c + i], c1[c]);
                }
            const float csum0 = red4((c0[0] + c0[1]) + (c0[2] + c0[3]));
            const float csum1 = red4((c1[0] + c1[1]) + (c1[2] + c1[3]));
            const float sumsel = low ? (odd ? asum1 : asum0) : (odd ? csum1 : csum0);
            const float fv = __builtin_amdgcn_rcpf(
                1.0f + __builtin_amdgcn_exp2f(fmaf(preF, sumsel, preFb)));
            const float fres = fmaf(postm, fv, posta);  // low: sigmoid, high: tanh
            const float hav = hjs * fres;               // roles 0/1 (fres = sigmoid)
            if (ks < 2) ha16h[2 * jg + ks] = (_Float16)hav;
            acs = fmaf(xe.z, fres, 0.9f * acs);         // roles 2/3
        }
    }

    // ---- Output: out[r] = sum_j (h_f + acc_f)[j] * W_out[j] + b_out ----
    float val = (low ? hjs : acs) * wosel;
#pragma unroll
    for (int m = 1; m < 64; m <<= 1) val += __shfl_xor(val, m);
    const int wave = t >> 6, lane = t & 63;
    if (lane == 0) red_s[wave] = val;
    __syncthreads();
    if (t == 0) {
        float o = bout;
#pragma unroll
        for (int w = 0; w < 4; ++w) o += red_s[w];
        out[r] = o;
    }
}

extern "C" void kernel_launch(void* const* d_in, const int* in_sizes, int n_in,
                              void* d_out, int out_size, void* d_ws, size_t ws_size,
                              hipStream_t stream) {
    const float* x     = (const float*)d_in[0];
    const float* W_in  = (const float*)d_in[1];
    const float* b_in  = (const float*)d_in[2];
    const float* W_rec = (const float*)d_in[3];
    const float* b_rec = (const float*)d_in[4];
    const float* tau   = (const float*)d_in[5];
    const float* W_att = (const float*)d_in[6];
    const float* b_att = (const float*)d_in[7];
    const float* W_ev  = (const float*)d_in[8];
    const float* b_ev  = (const float*)d_in[9];
    const float* W_acc = (const float*)d_in[10];
    const float* b_acc = (const float*)d_in[11];
    const float* W_out = (const float*)d_in[12];
    const float* b_out = (const float*)d_in[13];

    float* out    = (float*)d_out;        // [256,1]
    float* out_ew = out + 256;            // [256,2048]

    clnm_kernel<<<256, 256, 0, stream>>>(x, W_in, b_in, W_rec, b_rec, tau,
                                         W_att, b_att, W_ev, b_ev,
                                         W_acc, b_acc, W_out, b_out,
                                         out, out_ew);
}